// Round 8
// baseline (578.524 us; speedup 1.0000x reference)
//
#include <hip/hip_runtime.h>

#define KP   15
#define HN   40
#define CIN  128
#define COUT 128
#define KDIM (KP*CIN)          // 1920
#define KP_EXT_INV (1.0f/1.2f)
#define GRID 640               // <= 3 blocks/CU * 256 CU; all co-resident
#define GBM  32
#define GBK  128

typedef __bf16 bf16x8 __attribute__((ext_vector_type(8)));
typedef __bf16 bf16x4 __attribute__((ext_vector_type(4)));
typedef float  f32x4  __attribute__((ext_vector_type(4)));

__device__ inline void async_copy16(const void* g, void* lds) {
    __builtin_amdgcn_global_load_lds(
        (const __attribute__((address_space(1))) unsigned int*)g,
        (__attribute__((address_space(3))) unsigned int*)lds, 16, 0, 0);
}
#define LGKM0() __asm__ __volatile__("s_waitcnt lgkmcnt(0)" ::: "memory")

// grid barrier: cells zeroed by host memset before launch; all GRID blocks
// are co-resident (capacity proof: LDS 41KB -> 3 blk/CU, 3*256=768 >= 640).
__device__ inline void gridbar(unsigned* cell) {
    __threadfence();                       // release my stores to device scope
    __syncthreads();
    if (threadIdx.x == 0) {
        __hip_atomic_fetch_add(cell, 1u, __ATOMIC_ACQ_REL, __HIP_MEMORY_SCOPE_AGENT);
        while (__hip_atomic_load(cell, __ATOMIC_ACQUIRE, __HIP_MEMORY_SCOPE_AGENT)
               < (unsigned)gridDim.x) {
            __builtin_amdgcn_s_sleep(2);
        }
    }
    __syncthreads();
    __threadfence();                       // acquire side
}

union SharedU {
    struct { float sW[32][133]; } p0;                                  // 17 KB
    struct { __bf16 sXt[4][4][128][8];
             float4 s_nd[4][HN]; int s_idx[4][HN]; } p1;               // 36 KB
    struct { __bf16 sA[GBM*GBK]; __bf16 sB[COUT*GBK]; } p2;            // 40 KB
};

// ---------------------------------------------------------------------------
// Single persistent kernel: prep -> barrier -> aggregate -> barrier -> gemm
// ---------------------------------------------------------------------------
__global__ __launch_bounds__(256, 3)
void kpconv_all(const float* __restrict__ q_pts,
                const float* __restrict__ s_pts,
                const int*   __restrict__ nb,
                const float* __restrict__ x,
                const float* __restrict__ kpts,
                const float* __restrict__ W,
                float* __restrict__ out,
                __bf16* __restrict__ wsA,   // [N][1920]
                __bf16* __restrict__ wsB,   // Wt [128][1920]
                __bf16* __restrict__ xb,    // [Ns][128]
                unsigned* __restrict__ bars,
                int N, int Ns, int nx)
{
    __shared__ SharedU sh;

    const int t    = threadIdx.x;
    const int wv   = t >> 6;
    const int l    = t & 63;
    const int m    = l & 15;
    const int q    = l >> 4;
    const int gtid = blockIdx.x * 256 + t;
    const int nthr = GRID * 256;

    // ==================== Phase 0: x -> bf16, W -> Wt ====================
    for (int i = gtid; i < nx / 8; i += nthr) {
        const int e0 = i * 8;
        const float4 f0 = *(const float4*)(x + e0);
        const float4 f1 = *(const float4*)(x + e0 + 4);
        bf16x8 v;
        v[0]=(__bf16)f0.x; v[1]=(__bf16)f0.y; v[2]=(__bf16)f0.z; v[3]=(__bf16)f0.w;
        v[4]=(__bf16)f1.x; v[5]=(__bf16)f1.y; v[6]=(__bf16)f1.z; v[7]=(__bf16)f1.w;
        *(bf16x8*)(xb + e0) = v;
    }
    if (blockIdx.x < KDIM / 32) {
        const int kc0 = blockIdx.x * 32;
        #pragma unroll
        for (int i = 0; i < 4; ++i) {
            const int off = t*4 + i*1024;
            const int r = off >> 7, c = off & 127;
            const float4 f = *(const float4*)(W + (size_t)(kc0 + r)*COUT + c);
            sh.p0.sW[r][c+0]=f.x; sh.p0.sW[r][c+1]=f.y;
            sh.p0.sW[r][c+2]=f.z; sh.p0.sW[r][c+3]=f.w;
        }
        __syncthreads();
        #pragma unroll
        for (int i = 0; i < 2; ++i) {
            const int id = t + i*256;
            const int d  = id >> 2, ch = id & 3;
            bf16x8 v;
            #pragma unroll
            for (int j = 0; j < 8; ++j) v[j] = (__bf16)sh.p0.sW[ch*8 + j][d];
            *(bf16x8*)(wsB + (size_t)d*KDIM + kc0 + ch*8) = v;
        }
    }

    gridbar(&bars[0]);

    // ==================== Phase 1: per-wave aggregation ====================
    {
        float kx=0.f, ky=0.f, kz=0.f;
        if (m < KP) { kx = kpts[m*3+0]; ky = kpts[m*3+1]; kz = kpts[m*3+2]; }
        const float kk  = kx*kx + ky*ky + kz*kz;
        const float kx2 = -2.f*kx, ky2 = -2.f*ky, kz2 = -2.f*kz;

        for (int n = blockIdx.x*4 + wv; n < N; n += GRID*4) {
            // geometry; |nd|^2 in .w
            if (l < HN) {
                int idx = nb[n*HN + l];
                float dx, dy, dz;
                if (idx >= 0 && idx < Ns) {
                    dx = s_pts[idx*3+0] - q_pts[n*3+0];
                    dy = s_pts[idx*3+1] - q_pts[n*3+1];
                    dz = s_pts[idx*3+2] - q_pts[n*3+2];
                } else { idx = 0; dx = dy = dz = 2.0e6f; }
                sh.p1.s_idx[wv][l] = idx;
                sh.p1.s_nd[wv][l]  = make_float4(dx, dy, dz, dx*dx+dy*dy+dz*dz);
            }
            LGKM0();

            uint4 g[5][2];
            #pragma unroll
            for (int it = 0; it < 5; ++it) {
                const int h0 = (it < 4) ? (it*8 + 2*q) : (32 + 2*q);
                g[it][0] = *(const uint4*)(xb + (size_t)sh.p1.s_idx[wv][h0  ]*CIN + m*8);
                g[it][1] = *(const uint4*)(xb + (size_t)sh.p1.s_idx[wv][h0+1]*CIN + m*8);
            }

            bf16x8 wfrag[2];
            #pragma unroll
            for (int ks = 0; ks < 2; ++ks) {
                #pragma unroll
                for (int j = 0; j < 8; ++j) {
                    const int h = ks*32 + q*8 + j;
                    float w = 0.f;
                    if (m < KP && h < HN) {
                        const float4 nd = sh.p1.s_nd[wv][h];
                        const float d2 = fmaf(nd.x, kx2,
                                         fmaf(nd.y, ky2,
                                         fmaf(nd.z, kz2, nd.w + kk)));
                        const float d = __builtin_amdgcn_sqrtf(d2);
                        w = fmaxf(fmaf(d, -KP_EXT_INV, 1.0f), 0.f);
                    }
                    wfrag[ks][j] = (__bf16)w;
                }
            }

            f32x4 acc[8];
            #pragma unroll
            for (int nt = 0; nt < 8; ++nt) acc[nt] = (f32x4){0.f,0.f,0.f,0.f};

            #pragma unroll
            for (int ks = 0; ks < 2; ++ks) {
                const int itBeg = ks ? 4 : 0;
                const int itEnd = ks ? 5 : 4;
                #pragma unroll
                for (int it = itBeg; it < itEnd; ++it) {
                    const unsigned av[4] = {g[it][0].x, g[it][0].y, g[it][0].z, g[it][0].w};
                    const unsigned bv[4] = {g[it][1].x, g[it][1].y, g[it][1].z, g[it][1].w};
                    const int hc = ks ? 0 : it;
                    unsigned* plane = (unsigned*)&sh.p1.sXt[wv][hc][0][0];
                    #pragma unroll
                    for (int j = 0; j < 8; ++j) {
                        const unsigned v = __builtin_amdgcn_perm(
                            bv[j>>1], av[j>>1], (j&1) ? 0x07060302u : 0x05040100u);
                        const int p = m*8 + (j ^ (m & 7));
                        plane[p*4 + q] = v;
                    }
                }
                LGKM0();
                #pragma unroll
                for (int nt = 0; nt < 8; ++nt) {
                    const int cc = nt*16 + m;
                    const int p  = (cc & ~7) | ((cc & 7) ^ ((cc >> 3) & 7));
                    bf16x8 xf = *(const bf16x8*)&sh.p1.sXt[wv][q][p][0];
                    acc[nt] = __builtin_amdgcn_mfma_f32_16x16x32_bf16(
                                  xf, wfrag[ks], acc[nt], 0, 0, 0);
                }
            }

            if (m < KP) {
                #pragma unroll
                for (int nt = 0; nt < 8; ++nt) {
                    bf16x4 v;
                    #pragma unroll
                    for (int r = 0; r < 4; ++r) v[r] = (__bf16)acc[nt][r];
                    *(bf16x4*)(wsA + (size_t)n*KDIM + m*CIN + nt*16 + q*4) = v;
                }
            }
        }
    }

    gridbar(&bars[1]);

    // ==================== Phase 2: GEMM out = wsA x Wt^T ====================
    {
        const int rA = t >> 4;
        const int pA = t & 15;

        for (int tile = blockIdx.x; tile < N / GBM; tile += GRID) {
            const int m0 = tile * GBM;

            f32x4 acc[2][2];
            #pragma unroll
            for (int i = 0; i < 2; ++i)
                #pragma unroll
                for (int j = 0; j < 2; ++j) acc[i][j] = (f32x4){0.f,0.f,0.f,0.f};

            for (int k0 = 0; k0 < KDIM; k0 += GBK) {
                #pragma unroll
                for (int pass = 0; pass < 2; ++pass) {
                    const int r  = rA + pass*16;
                    const int ch = pA ^ (r & 15);
                    async_copy16(wsA + (size_t)(m0 + r)*KDIM + k0 + ch*8,
                                 (char*)sh.p2.sA + pass*4096 + wv*1024 + l*16);
                }
                #pragma unroll
                for (int pass = 0; pass < 8; ++pass) {
                    const int r  = rA + pass*16;
                    const int ch = pA ^ (r & 15);
                    async_copy16(wsB + (size_t)r*KDIM + k0 + ch*8,
                                 (char*)sh.p2.sB + pass*4096 + wv*1024 + l*16);
                }
                __syncthreads();

                #pragma unroll
                for (int ks = 0; ks < 4; ++ks) {
                    bf16x8 af[2], bfr[2];
                    #pragma unroll
                    for (int mt = 0; mt < 2; ++mt) {
                        const int row = mt*16 + m;
                        const int p   = (ks*4 + q) ^ (row & 15);
                        af[mt] = *(const bf16x8*)&sh.p2.sA[row*GBK + p*8];
                    }
                    #pragma unroll
                    for (int j = 0; j < 2; ++j) {
                        const int row = (wv*2 + j)*16 + m;
                        const int p   = (ks*4 + q) ^ (row & 15);
                        bfr[j] = *(const bf16x8*)&sh.p2.sB[row*GBK + p*8];
                    }
                    #pragma unroll
                    for (int mt = 0; mt < 2; ++mt)
                        #pragma unroll
                        for (int j = 0; j < 2; ++j)
                            acc[mt][j] = __builtin_amdgcn_mfma_f32_16x16x32_bf16(
                                             af[mt], bfr[j], acc[mt][j], 0, 0, 0);
                }
                __syncthreads();
            }

            #pragma unroll
            for (int mt = 0; mt < 2; ++mt)
                #pragma unroll
                for (int j = 0; j < 2; ++j)
                    #pragma unroll
                    for (int r = 0; r < 4; ++r)
                        out[(size_t)(m0 + mt*16 + q*4 + r)*COUT
                            + (wv*2+j)*16 + m] = acc[mt][j][r];
        }
    }
}

// ---------------------------------------------------------------------------
// Fallback (round-1 fused kernel) if ws too small / shape mismatch
// ---------------------------------------------------------------------------
#define TM 8
#define WSTR (KP*CIN + 4)

__global__ __launch_bounds__(256, 2)
void kpconv_fused(const float* __restrict__ q_pts,
                  const float* __restrict__ s_pts,
                  const int*   __restrict__ nb,
                  const float* __restrict__ x,
                  const float* __restrict__ kpts,
                  const float* __restrict__ W,
                  float* __restrict__ out,
                  int N, int Ns)
{
    __shared__ float s_kp[KP*3];
    __shared__ float s_nd2[HN*3];
    __shared__ int   s_idx2[HN];
    __shared__ float s_w[KP][HN];
    __shared__ float s_wt[TM*WSTR];

    const int t  = threadIdx.x;
    const int n0 = (int)blockIdx.x * TM;
    if (t < KP*3) s_kp[t] = kpts[t];
    const int c = t & (CIN-1);
    const int g = t >> 7;

    for (int mm = 0; mm < TM; ++mm) {
        const int n = n0 + mm;
        if (t < HN) {
            float dx = 1e6f, dy = 1e6f, dz = 1e6f;
            int idx = 0;
            if (n < N) {
                idx = nb[n*HN + t];
                if (idx >= 0 && idx < Ns) {
                    dx = s_pts[idx*3+0] - q_pts[n*3+0];
                    dy = s_pts[idx*3+1] - q_pts[n*3+1];
                    dz = s_pts[idx*3+2] - q_pts[n*3+2];
                } else idx = 0;
            }
            s_idx2[t] = idx;
            s_nd2[t*3+0] = dx; s_nd2[t*3+1] = dy; s_nd2[t*3+2] = dz;
        }
        __syncthreads();
        for (int task = t; task < KP*HN; task += 256) {
            const int k = task / HN;
            const int h = task - k*HN;
            const float dx = s_nd2[h*3+0] - s_kp[k*3+0];
            const float dy = s_nd2[h*3+1] - s_kp[k*3+1];
            const float dz = s_nd2[h*3+2] - s_kp[k*3+2];
            s_w[k][h] = fmaxf(1.0f - sqrtf(dx*dx+dy*dy+dz*dz)*KP_EXT_INV, 0.0f);
        }
        __syncthreads();
        float facc[8];
        #pragma unroll
        for (int j = 0; j < 8; ++j) facc[j] = 0.0f;
        #pragma unroll 8
        for (int h = 0; h < HN; ++h) {
            const float xv = x[s_idx2[h]*CIN + c];
            #pragma unroll
            for (int j = 0; j < 8; ++j) {
                const int k = g + 2*j;
                if (k < KP) facc[j] += s_w[k][h] * xv;
            }
        }
        #pragma unroll
        for (int j = 0; j < 8; ++j) {
            const int k = g + 2*j;
            if (k < KP) s_wt[mm*WSTR + k*CIN + c] = facc[j];
        }
        __syncthreads();
    }

    const int m3 = t >> 5;
    const int d0 = (t & 31) * 4;
    const float* wm = &s_wt[m3*WSTR];
    float ax = 0.f, ay = 0.f, az = 0.f, aw = 0.f;
    #pragma unroll 4
    for (int kc = 0; kc < KP*CIN; ++kc) {
        const float  wvv = wm[kc];
        const float4 wr = *(const float4*)&W[kc*COUT + d0];
        ax += wvv * wr.x; ay += wvv * wr.y; az += wvv * wr.z; aw += wvv * wr.w;
    }
    const int n = n0 + m3;
    if (n < N) {
        float4 o; o.x = ax; o.y = ay; o.z = az; o.w = aw;
        *(float4*)&out[n*COUT + d0] = o;
    }
}

// ---------------------------------------------------------------------------
extern "C" void kernel_launch(void* const* d_in, const int* in_sizes, int n_in,
                              void* d_out, int out_size, void* d_ws, size_t ws_size,
                              hipStream_t stream) {
    const float* q_pts = (const float*)d_in[0];
    const float* s_pts = (const float*)d_in[1];
    const int*   nb    = (const int*)  d_in[2];
    const float* x     = (const float*)d_in[3];
    const float* kpts  = (const float*)d_in[4];
    const float* W     = (const float*)d_in[5];
    float* out = (float*)d_out;

    const int N  = in_sizes[0] / 3;
    const int Ns = in_sizes[1] / 3;
    const int nx = in_sizes[3];            // Ns*CIN

    const size_t needA = (size_t)N * KDIM * sizeof(__bf16);
    const size_t needB = (size_t)COUT * KDIM * sizeof(__bf16);
    const size_t needX = (size_t)nx * sizeof(__bf16);
    size_t barOff = needA + needB + needX;
    barOff = (barOff + 63) & ~(size_t)63;

    if (ws_size >= barOff + 128 && (N % GBM) == 0 && (nx % 8) == 0
        && (KDIM % GBK) == 0) {
        __bf16* wsA = (__bf16*)d_ws;
        __bf16* wsB = (__bf16*)((char*)d_ws + needA);
        __bf16* wsX = (__bf16*)((char*)d_ws + needA + needB);
        unsigned* bars = (unsigned*)((char*)d_ws + barOff);

        hipMemsetAsync(bars, 0, 128, stream);
        hipLaunchKernelGGL(kpconv_all, dim3(GRID), dim3(256), 0, stream,
                           q_pts, s_pts, nb, x, kpts, W, out,
                           wsA, wsB, wsX, bars, N, Ns, nx);
    } else {
        const int grid = (N + TM - 1) / TM;
        hipLaunchKernelGGL(kpconv_fused, dim3(grid), dim3(256), 0, stream,
                           q_pts, s_pts, nb, x, kpts, W, out, N, Ns);
    }
}

// Round 9
// 446.891 us; speedup vs baseline: 1.2946x; 1.2946x over previous
//
#include <hip/hip_runtime.h>

#define KP   15
#define HN   40
#define CIN  128
#define COUT 128
#define KDIM (KP*CIN)          // 1920
#define KP_EXT_INV (1.0f/1.2f)
#define GRID 640               // <= 3 blocks/CU * 256 CU; all co-resident
#define GBM  32
#define GBK  128

typedef __bf16 bf16x8 __attribute__((ext_vector_type(8)));
typedef __bf16 bf16x4 __attribute__((ext_vector_type(4)));
typedef float  f32x4  __attribute__((ext_vector_type(4)));

__device__ inline void async_copy16(const void* g, void* lds) {
    __builtin_amdgcn_global_load_lds(
        (const __attribute__((address_space(1))) unsigned int*)g,
        (__attribute__((address_space(3))) unsigned int*)lds, 16, 0, 0);
}
#define LGKM0() __asm__ __volatile__("s_waitcnt lgkmcnt(0)" ::: "memory")

// Grid barrier, poll-storm-free version:
//  - counter (RMW) and flag (read-only polls) on SEPARATE 64B lines
//  - waiters poll RELAXED (no per-poll buffer_inv) with ~3.4us backoff
//  - release via single flag store by the last arriver -> immediate detection
//  - one seq_cst threadfence after provides acquire for the whole block
// Cells zeroed by host memset before launch; all GRID blocks co-resident
// (capacity: LDS 40KB -> 3 blk/CU by LDS, 3*256=768 >= 640).
__device__ inline void gridbar(unsigned* cnt, unsigned* flag) {
    __threadfence();                       // release my stores
    __syncthreads();
    if (threadIdx.x == 0) {
        const unsigned old = __hip_atomic_fetch_add(
            cnt, 1u, __ATOMIC_ACQ_REL, __HIP_MEMORY_SCOPE_AGENT);
        if (old == (unsigned)gridDim.x - 1u) {
            __hip_atomic_store(flag, 1u, __ATOMIC_RELEASE,
                               __HIP_MEMORY_SCOPE_AGENT);
        } else {
            while (__hip_atomic_load(flag, __ATOMIC_RELAXED,
                                     __HIP_MEMORY_SCOPE_AGENT) == 0u) {
                __builtin_amdgcn_s_sleep(127);   // ~3.4 us backoff
            }
        }
    }
    __syncthreads();
    __threadfence();                       // acquire side (seq_cst)
}

union SharedU {
    struct { float sW[32][133]; } p0;                                  // 17 KB
    struct { __bf16 sXt[4][4][128][8];
             float4 s_nd[4][HN]; int s_idx[4][HN]; } p1;               // 36 KB
    struct { __bf16 sA[GBM*GBK]; __bf16 sB[COUT*GBK]; } p2;            // 40 KB
};

// ---------------------------------------------------------------------------
// Single persistent kernel: prep -> barrier -> aggregate -> barrier -> gemm
// ---------------------------------------------------------------------------
__global__ __launch_bounds__(256, 3)
void kpconv_all(const float* __restrict__ q_pts,
                const float* __restrict__ s_pts,
                const int*   __restrict__ nb,
                const float* __restrict__ x,
                const float* __restrict__ kpts,
                const float* __restrict__ W,
                float* __restrict__ out,
                __bf16* __restrict__ wsA,   // [N][1920]
                __bf16* __restrict__ wsB,   // Wt [128][1920]
                __bf16* __restrict__ xb,    // [Ns][128]
                unsigned* __restrict__ bars,
                int N, int Ns, int nx)
{
    __shared__ SharedU sh;

    const int t    = threadIdx.x;
    const int wv   = t >> 6;
    const int l    = t & 63;
    const int m    = l & 15;
    const int q    = l >> 4;
    const int gtid = blockIdx.x * 256 + t;
    const int nthr = GRID * 256;

    // ==================== Phase 0: x -> bf16, W -> Wt ====================
    for (int i = gtid; i < nx / 8; i += nthr) {
        const int e0 = i * 8;
        const float4 f0 = *(const float4*)(x + e0);
        const float4 f1 = *(const float4*)(x + e0 + 4);
        bf16x8 v;
        v[0]=(__bf16)f0.x; v[1]=(__bf16)f0.y; v[2]=(__bf16)f0.z; v[3]=(__bf16)f0.w;
        v[4]=(__bf16)f1.x; v[5]=(__bf16)f1.y; v[6]=(__bf16)f1.z; v[7]=(__bf16)f1.w;
        *(bf16x8*)(xb + e0) = v;
    }
    if (blockIdx.x < KDIM / 32) {
        const int kc0 = blockIdx.x * 32;
        #pragma unroll
        for (int i = 0; i < 4; ++i) {
            const int off = t*4 + i*1024;
            const int r = off >> 7, c = off & 127;
            const float4 f = *(const float4*)(W + (size_t)(kc0 + r)*COUT + c);
            sh.p0.sW[r][c+0]=f.x; sh.p0.sW[r][c+1]=f.y;
            sh.p0.sW[r][c+2]=f.z; sh.p0.sW[r][c+3]=f.w;
        }
        __syncthreads();
        #pragma unroll
        for (int i = 0; i < 2; ++i) {
            const int id = t + i*256;
            const int d  = id >> 2, ch = id & 3;
            bf16x8 v;
            #pragma unroll
            for (int j = 0; j < 8; ++j) v[j] = (__bf16)sh.p0.sW[ch*8 + j][d];
            *(bf16x8*)(wsB + (size_t)d*KDIM + kc0 + ch*8) = v;
        }
    }

    gridbar(&bars[0], &bars[16]);

    // ==================== Phase 1: per-wave aggregation ====================
    {
        float kx=0.f, ky=0.f, kz=0.f;
        if (m < KP) { kx = kpts[m*3+0]; ky = kpts[m*3+1]; kz = kpts[m*3+2]; }
        const float kk  = kx*kx + ky*ky + kz*kz;
        const float kx2 = -2.f*kx, ky2 = -2.f*ky, kz2 = -2.f*kz;

        for (int n = blockIdx.x*4 + wv; n < N; n += GRID*4) {
            // geometry; |nd|^2 in .w
            if (l < HN) {
                int idx = nb[n*HN + l];
                float dx, dy, dz;
                if (idx >= 0 && idx < Ns) {
                    dx = s_pts[idx*3+0] - q_pts[n*3+0];
                    dy = s_pts[idx*3+1] - q_pts[n*3+1];
                    dz = s_pts[idx*3+2] - q_pts[n*3+2];
                } else { idx = 0; dx = dy = dz = 2.0e6f; }
                sh.p1.s_idx[wv][l] = idx;
                sh.p1.s_nd[wv][l]  = make_float4(dx, dy, dz, dx*dx+dy*dy+dz*dz);
            }
            LGKM0();

            uint4 g[5][2];
            #pragma unroll
            for (int it = 0; it < 5; ++it) {
                const int h0 = (it < 4) ? (it*8 + 2*q) : (32 + 2*q);
                g[it][0] = *(const uint4*)(xb + (size_t)sh.p1.s_idx[wv][h0  ]*CIN + m*8);
                g[it][1] = *(const uint4*)(xb + (size_t)sh.p1.s_idx[wv][h0+1]*CIN + m*8);
            }

            bf16x8 wfrag[2];
            #pragma unroll
            for (int ks = 0; ks < 2; ++ks) {
                #pragma unroll
                for (int j = 0; j < 8; ++j) {
                    const int h = ks*32 + q*8 + j;
                    float w = 0.f;
                    if (m < KP && h < HN) {
                        const float4 nd = sh.p1.s_nd[wv][h];
                        const float d2 = fmaf(nd.x, kx2,
                                         fmaf(nd.y, ky2,
                                         fmaf(nd.z, kz2, nd.w + kk)));
                        const float d = __builtin_amdgcn_sqrtf(d2);
                        w = fmaxf(fmaf(d, -KP_EXT_INV, 1.0f), 0.f);
                    }
                    wfrag[ks][j] = (__bf16)w;
                }
            }

            f32x4 acc[8];
            #pragma unroll
            for (int nt = 0; nt < 8; ++nt) acc[nt] = (f32x4){0.f,0.f,0.f,0.f};

            #pragma unroll
            for (int ks = 0; ks < 2; ++ks) {
                const int itBeg = ks ? 4 : 0;
                const int itEnd = ks ? 5 : 4;
                #pragma unroll
                for (int it = itBeg; it < itEnd; ++it) {
                    const unsigned av[4] = {g[it][0].x, g[it][0].y, g[it][0].z, g[it][0].w};
                    const unsigned bv[4] = {g[it][1].x, g[it][1].y, g[it][1].z, g[it][1].w};
                    const int hc = ks ? 0 : it;
                    unsigned* plane = (unsigned*)&sh.p1.sXt[wv][hc][0][0];
                    #pragma unroll
                    for (int j = 0; j < 8; ++j) {
                        const unsigned v = __builtin_amdgcn_perm(
                            bv[j>>1], av[j>>1], (j&1) ? 0x07060302u : 0x05040100u);
                        const int p = m*8 + (j ^ (m & 7));
                        plane[p*4 + q] = v;
                    }
                }
                LGKM0();
                #pragma unroll
                for (int nt = 0; nt < 8; ++nt) {
                    const int cc = nt*16 + m;
                    const int p  = (cc & ~7) | ((cc & 7) ^ ((cc >> 3) & 7));
                    bf16x8 xf = *(const bf16x8*)&sh.p1.sXt[wv][q][p][0];
                    acc[nt] = __builtin_amdgcn_mfma_f32_16x16x32_bf16(
                                  xf, wfrag[ks], acc[nt], 0, 0, 0);
                }
            }

            if (m < KP) {
                #pragma unroll
                for (int nt = 0; nt < 8; ++nt) {
                    bf16x4 v;
                    #pragma unroll
                    for (int r = 0; r < 4; ++r) v[r] = (__bf16)acc[nt][r];
                    *(bf16x4*)(wsA + (size_t)n*KDIM + m*CIN + nt*16 + q*4) = v;
                }
            }
        }
    }

    gridbar(&bars[1], &bars[17]);

    // ==================== Phase 2: GEMM out = wsA x Wt^T ====================
    {
        const int rA = t >> 4;
        const int pA = t & 15;

        for (int tile = blockIdx.x; tile < N / GBM; tile += GRID) {
            const int m0 = tile * GBM;

            f32x4 acc[2][2];
            #pragma unroll
            for (int i = 0; i < 2; ++i)
                #pragma unroll
                for (int j = 0; j < 2; ++j) acc[i][j] = (f32x4){0.f,0.f,0.f,0.f};

            for (int k0 = 0; k0 < KDIM; k0 += GBK) {
                #pragma unroll
                for (int pass = 0; pass < 2; ++pass) {
                    const int r  = rA + pass*16;
                    const int ch = pA ^ (r & 15);
                    async_copy16(wsA + (size_t)(m0 + r)*KDIM + k0 + ch*8,
                                 (char*)sh.p2.sA + pass*4096 + wv*1024 + l*16);
                }
                #pragma unroll
                for (int pass = 0; pass < 8; ++pass) {
                    const int r  = rA + pass*16;
                    const int ch = pA ^ (r & 15);
                    async_copy16(wsB + (size_t)r*KDIM + k0 + ch*8,
                                 (char*)sh.p2.sB + pass*4096 + wv*1024 + l*16);
                }
                __syncthreads();

                #pragma unroll
                for (int ks = 0; ks < 4; ++ks) {
                    bf16x8 af[2], bfr[2];
                    #pragma unroll
                    for (int mt = 0; mt < 2; ++mt) {
                        const int row = mt*16 + m;
                        const int p   = (ks*4 + q) ^ (row & 15);
                        af[mt] = *(const bf16x8*)&sh.p2.sA[row*GBK + p*8];
                    }
                    #pragma unroll
                    for (int j = 0; j < 2; ++j) {
                        const int row = (wv*2 + j)*16 + m;
                        const int p   = (ks*4 + q) ^ (row & 15);
                        bfr[j] = *(const bf16x8*)&sh.p2.sB[row*GBK + p*8];
                    }
                    #pragma unroll
                    for (int mt = 0; mt < 2; ++mt)
                        #pragma unroll
                        for (int j = 0; j < 2; ++j)
                            acc[mt][j] = __builtin_amdgcn_mfma_f32_16x16x32_bf16(
                                             af[mt], bfr[j], acc[mt][j], 0, 0, 0);
                }
                __syncthreads();
            }

            #pragma unroll
            for (int mt = 0; mt < 2; ++mt)
                #pragma unroll
                for (int j = 0; j < 2; ++j)
                    #pragma unroll
                    for (int r = 0; r < 4; ++r)
                        out[(size_t)(m0 + mt*16 + q*4 + r)*COUT
                            + (wv*2+j)*16 + m] = acc[mt][j][r];
        }
    }
}

// ---------------------------------------------------------------------------
// Fallback (round-1 fused kernel) if ws too small / shape mismatch
// ---------------------------------------------------------------------------
#define TM 8
#define WSTR (KP*CIN + 4)

__global__ __launch_bounds__(256, 2)
void kpconv_fused(const float* __restrict__ q_pts,
                  const float* __restrict__ s_pts,
                  const int*   __restrict__ nb,
                  const float* __restrict__ x,
                  const float* __restrict__ kpts,
                  const float* __restrict__ W,
                  float* __restrict__ out,
                  int N, int Ns)
{
    __shared__ float s_kp[KP*3];
    __shared__ float s_nd2[HN*3];
    __shared__ int   s_idx2[HN];
    __shared__ float s_w[KP][HN];
    __shared__ float s_wt[TM*WSTR];

    const int t  = threadIdx.x;
    const int n0 = (int)blockIdx.x * TM;
    if (t < KP*3) s_kp[t] = kpts[t];
    const int c = t & (CIN-1);
    const int g = t >> 7;

    for (int mm = 0; mm < TM; ++mm) {
        const int n = n0 + mm;
        if (t < HN) {
            float dx = 1e6f, dy = 1e6f, dz = 1e6f;
            int idx = 0;
            if (n < N) {
                idx = nb[n*HN + t];
                if (idx >= 0 && idx < Ns) {
                    dx = s_pts[idx*3+0] - q_pts[n*3+0];
                    dy = s_pts[idx*3+1] - q_pts[n*3+1];
                    dz = s_pts[idx*3+2] - q_pts[n*3+2];
                } else idx = 0;
            }
            s_idx2[t] = idx;
            s_nd2[t*3+0] = dx; s_nd2[t*3+1] = dy; s_nd2[t*3+2] = dz;
        }
        __syncthreads();
        for (int task = t; task < KP*HN; task += 256) {
            const int k = task / HN;
            const int h = task - k*HN;
            const float dx = s_nd2[h*3+0] - s_kp[k*3+0];
            const float dy = s_nd2[h*3+1] - s_kp[k*3+1];
            const float dz = s_nd2[h*3+2] - s_kp[k*3+2];
            s_w[k][h] = fmaxf(1.0f - sqrtf(dx*dx+dy*dy+dz*dz)*KP_EXT_INV, 0.0f);
        }
        __syncthreads();
        float facc[8];
        #pragma unroll
        for (int j = 0; j < 8; ++j) facc[j] = 0.0f;
        #pragma unroll 8
        for (int h = 0; h < HN; ++h) {
            const float xv = x[s_idx2[h]*CIN + c];
            #pragma unroll
            for (int j = 0; j < 8; ++j) {
                const int k = g + 2*j;
                if (k < KP) facc[j] += s_w[k][h] * xv;
            }
        }
        #pragma unroll
        for (int j = 0; j < 8; ++j) {
            const int k = g + 2*j;
            if (k < KP) s_wt[mm*WSTR + k*CIN + c] = facc[j];
        }
        __syncthreads();
    }

    const int m3 = t >> 5;
    const int d0 = (t & 31) * 4;
    const float* wm = &s_wt[m3*WSTR];
    float ax = 0.f, ay = 0.f, az = 0.f, aw = 0.f;
    #pragma unroll 4
    for (int kc = 0; kc < KP*CIN; ++kc) {
        const float  wvv = wm[kc];
        const float4 wr = *(const float4*)&W[kc*COUT + d0];
        ax += wvv * wr.x; ay += wvv * wr.y; az += wvv * wr.z; aw += wvv * wr.w;
    }
    const int n = n0 + m3;
    if (n < N) {
        float4 o; o.x = ax; o.y = ay; o.z = az; o.w = aw;
        *(float4*)&out[n*COUT + d0] = o;
    }
}

// ---------------------------------------------------------------------------
extern "C" void kernel_launch(void* const* d_in, const int* in_sizes, int n_in,
                              void* d_out, int out_size, void* d_ws, size_t ws_size,
                              hipStream_t stream) {
    const float* q_pts = (const float*)d_in[0];
    const float* s_pts = (const float*)d_in[1];
    const int*   nb    = (const int*)  d_in[2];
    const float* x     = (const float*)d_in[3];
    const float* kpts  = (const float*)d_in[4];
    const float* W     = (const float*)d_in[5];
    float* out = (float*)d_out;

    const int N  = in_sizes[0] / 3;
    const int Ns = in_sizes[1] / 3;
    const int nx = in_sizes[3];            // Ns*CIN

    const size_t needA = (size_t)N * KDIM * sizeof(__bf16);
    const size_t needB = (size_t)COUT * KDIM * sizeof(__bf16);
    const size_t needX = (size_t)nx * sizeof(__bf16);
    size_t barOff = needA + needB + needX;
    barOff = (barOff + 63) & ~(size_t)63;

    if (ws_size >= barOff + 128 && (N % GBM) == 0 && (nx % 8) == 0
        && (KDIM % GBK) == 0) {
        __bf16* wsA = (__bf16*)d_ws;
        __bf16* wsB = (__bf16*)((char*)d_ws + needA);
        __bf16* wsX = (__bf16*)((char*)d_ws + needA + needB);
        unsigned* bars = (unsigned*)((char*)d_ws + barOff);

        hipMemsetAsync(bars, 0, 128, stream);
        hipLaunchKernelGGL(kpconv_all, dim3(GRID), dim3(256), 0, stream,
                           q_pts, s_pts, nb, x, kpts, W, out,
                           wsA, wsB, wsX, bars, N, Ns, nx);
    } else {
        const int grid = (N + TM - 1) / TM;
        hipLaunchKernelGGL(kpconv_fused, dim3(grid), dim3(256), 0, stream,
                           q_pts, s_pts, nb, x, kpts, W, out, N, Ns);
    }
}

// Round 10
// 143.334 us; speedup vs baseline: 4.0362x; 3.1178x over previous
//
#include <hip/hip_runtime.h>

#define KP   15
#define HN   40
#define CIN  128
#define COUT 128
#define KDIM (KP*CIN)          // 1920
#define KP_EXT_INV (1.0f/1.2f)
#define GBM  32
#define GBK  128

typedef __bf16 bf16x8 __attribute__((ext_vector_type(8)));
typedef __bf16 bf16x4 __attribute__((ext_vector_type(4)));
typedef float  f32x4  __attribute__((ext_vector_type(4)));

__device__ inline void async_copy16(const void* g, void* lds) {
    __builtin_amdgcn_global_load_lds(
        (const __attribute__((address_space(1))) unsigned int*)g,
        (__attribute__((address_space(3))) unsigned int*)lds, 16, 0, 0);
}
#define LGKM0() __asm__ __volatile__("s_waitcnt lgkmcnt(0)" ::: "memory")
#define VM0()   __asm__ __volatile__("s_waitcnt vmcnt(0)"   ::: "memory")

// ---------------------------------------------------------------------------
// Kernel 1 (prep): x f32 -> xb bf16 (coalesced); W [1920][128] -> Wt [128][1920]
// ---------------------------------------------------------------------------
__global__ __launch_bounds__(256)
void kpconv_prep(const float* __restrict__ x, const float* __restrict__ W,
                 __bf16* __restrict__ xb, __bf16* __restrict__ Wt,
                 int nx_elems, int nxB)
{
    __shared__ float sW[32][133];
    const int b = blockIdx.x;
    const int t = threadIdx.x;

    if (b < nxB) {
        const int e0 = (b*256 + t) * 8;
        if (e0 + 8 <= nx_elems) {
            const float4 f0 = *(const float4*)(x + e0);
            const float4 f1 = *(const float4*)(x + e0 + 4);
            bf16x8 v;
            v[0]=(__bf16)f0.x; v[1]=(__bf16)f0.y; v[2]=(__bf16)f0.z; v[3]=(__bf16)f0.w;
            v[4]=(__bf16)f1.x; v[5]=(__bf16)f1.y; v[6]=(__bf16)f1.z; v[7]=(__bf16)f1.w;
            *(bf16x8*)(xb + e0) = v;
        } else {
            for (int e = e0; e < nx_elems; ++e) xb[e] = (__bf16)x[e];
        }
    } else {
        const int kc0 = (b - nxB) * 32;
        #pragma unroll
        for (int i = 0; i < 4; ++i) {
            const int off = t*4 + i*1024;
            const int r = off >> 7, c = off & 127;
            const float4 f = *(const float4*)(W + (size_t)(kc0 + r)*COUT + c);
            sW[r][c+0]=f.x; sW[r][c+1]=f.y; sW[r][c+2]=f.z; sW[r][c+3]=f.w;
        }
        __syncthreads();
        #pragma unroll
        for (int i = 0; i < 2; ++i) {
            const int id = t + i*256;
            const int d  = id >> 2, ch = id & 3;
            bf16x8 v;
            #pragma unroll
            for (int j = 0; j < 8; ++j) v[j] = (__bf16)sW[ch*8 + j][d];
            *(bf16x8*)(Wt + (size_t)d*KDIM + kc0 + ch*8) = v;
        }
    }
}

// ---------------------------------------------------------------------------
// Kernel 2 (main): 1 block = 32 points. NO grid sync needed — the GEMM tile's
// A-rows are exactly the 32 points this block aggregated.
// Phase A: 4 waves x 8 points, R7's verified per-wave MFMA aggregation,
//          weighted rows -> wsA (global scratch; stays L2-hot, same XCD).
// Drain:   s_waitcnt vmcnt(0) + __syncthreads().
// Phase B: R7's staged GEMM (BM=32, BK=128), direct stores, no atomics.
// ---------------------------------------------------------------------------
union SharedU {
    struct { __bf16 sXt[4][4][128][8];               // 32 KB
             float4 s_nd[4][HN]; int s_idx[4][HN]; } a;
    struct { __bf16 sA[GBM*GBK]; __bf16 sB[COUT*GBK]; } b;   // 40 KB
};

__global__ __launch_bounds__(256, 3)
void kpconv_main(const float* __restrict__ q_pts,
                 const float* __restrict__ s_pts,
                 const int*   __restrict__ nb,
                 const __bf16* __restrict__ xb,
                 const float* __restrict__ kpts,
                 const __bf16* __restrict__ Wt,
                 __bf16* __restrict__ wsA,
                 float* __restrict__ out, int N, int Ns)
{
    __shared__ SharedU sh;

    const int t  = threadIdx.x;
    const int wv = t >> 6;
    const int l  = t & 63;
    const int m  = l & 15;
    const int q  = l >> 4;
    const int m0 = blockIdx.x * GBM;

    // ==================== Phase A: aggregate 32 points ====================
    {
        float kx=0.f, ky=0.f, kz=0.f;
        if (m < KP) { kx = kpts[m*3+0]; ky = kpts[m*3+1]; kz = kpts[m*3+2]; }
        const float kk  = kx*kx + ky*ky + kz*kz;
        const float kx2 = -2.f*kx, ky2 = -2.f*ky, kz2 = -2.f*kz;

        for (int pi = 0; pi < 8; ++pi) {
            const int n = m0 + wv*8 + pi;

            // geometry; |nd|^2 in .w  (wave-local buffers, lgkm-only sync)
            if (l < HN) {
                int idx = nb[n*HN + l];
                float dx, dy, dz;
                if (idx >= 0 && idx < Ns) {
                    dx = s_pts[idx*3+0] - q_pts[n*3+0];
                    dy = s_pts[idx*3+1] - q_pts[n*3+1];
                    dz = s_pts[idx*3+2] - q_pts[n*3+2];
                } else { idx = 0; dx = dy = dz = 2.0e6f; }
                sh.a.s_idx[wv][l] = idx;
                sh.a.s_nd[wv][l]  = make_float4(dx, dy, dz, dx*dx+dy*dy+dz*dz);
            }
            LGKM0();

            uint4 g[5][2];
            #pragma unroll
            for (int it = 0; it < 5; ++it) {
                const int h0 = (it < 4) ? (it*8 + 2*q) : (32 + 2*q);
                g[it][0] = *(const uint4*)(xb + (size_t)sh.a.s_idx[wv][h0  ]*CIN + m*8);
                g[it][1] = *(const uint4*)(xb + (size_t)sh.a.s_idx[wv][h0+1]*CIN + m*8);
            }

            bf16x8 wfrag[2];
            #pragma unroll
            for (int ks = 0; ks < 2; ++ks) {
                #pragma unroll
                for (int j = 0; j < 8; ++j) {
                    const int h = ks*32 + q*8 + j;
                    float w = 0.f;
                    if (m < KP && h < HN) {
                        const float4 nd = sh.a.s_nd[wv][h];
                        const float d2 = fmaf(nd.x, kx2,
                                         fmaf(nd.y, ky2,
                                         fmaf(nd.z, kz2, nd.w + kk)));
                        const float d = __builtin_amdgcn_sqrtf(d2);
                        w = fmaxf(fmaf(d, -KP_EXT_INV, 1.0f), 0.f);
                    }
                    wfrag[ks][j] = (__bf16)w;
                }
            }

            f32x4 acc[8];
            #pragma unroll
            for (int nt = 0; nt < 8; ++nt) acc[nt] = (f32x4){0.f,0.f,0.f,0.f};

            #pragma unroll
            for (int ks = 0; ks < 2; ++ks) {
                const int itBeg = ks ? 4 : 0;
                const int itEnd = ks ? 5 : 4;
                #pragma unroll
                for (int it = itBeg; it < itEnd; ++it) {
                    const unsigned av[4] = {g[it][0].x, g[it][0].y, g[it][0].z, g[it][0].w};
                    const unsigned bv[4] = {g[it][1].x, g[it][1].y, g[it][1].z, g[it][1].w};
                    const int hc = ks ? 0 : it;
                    unsigned* plane = (unsigned*)&sh.a.sXt[wv][hc][0][0];
                    #pragma unroll
                    for (int j = 0; j < 8; ++j) {
                        const unsigned v = __builtin_amdgcn_perm(
                            bv[j>>1], av[j>>1], (j&1) ? 0x07060302u : 0x05040100u);
                        const int p = m*8 + (j ^ (m & 7));
                        plane[p*4 + q] = v;
                    }
                }
                LGKM0();
                #pragma unroll
                for (int nt = 0; nt < 8; ++nt) {
                    const int cc = nt*16 + m;
                    const int p  = (cc & ~7) | ((cc & 7) ^ ((cc >> 3) & 7));
                    bf16x8 xf = *(const bf16x8*)&sh.a.sXt[wv][q][p][0];
                    acc[nt] = __builtin_amdgcn_mfma_f32_16x16x32_bf16(
                                  xf, wfrag[ks], acc[nt], 0, 0, 0);
                }
            }

            if (m < KP) {
                #pragma unroll
                for (int nt = 0; nt < 8; ++nt) {
                    bf16x4 v;
                    #pragma unroll
                    for (int r = 0; r < 4; ++r) v[r] = (__bf16)acc[nt][r];
                    *(bf16x4*)(wsA + (size_t)n*KDIM + m*CIN + nt*16 + q*4) = v;
                }
            }
        }
    }

    // wsA writes -> visible to this block's DMA reads (same CU -> same L2)
    VM0();
    __syncthreads();

    // ==================== Phase B: GEMM tile [m0, m0+32) ====================
    {
        const int rA = t >> 4;
        const int pA = t & 15;

        f32x4 acc[2][2];
        #pragma unroll
        for (int i = 0; i < 2; ++i)
            #pragma unroll
            for (int j = 0; j < 2; ++j) acc[i][j] = (f32x4){0.f,0.f,0.f,0.f};

        for (int k0 = 0; k0 < KDIM; k0 += GBK) {
            #pragma unroll
            for (int pass = 0; pass < 2; ++pass) {
                const int r  = rA + pass*16;
                const int ch = pA ^ (r & 15);
                async_copy16(wsA + (size_t)(m0 + r)*KDIM + k0 + ch*8,
                             (char*)sh.b.sA + pass*4096 + wv*1024 + l*16);
            }
            #pragma unroll
            for (int pass = 0; pass < 8; ++pass) {
                const int r  = rA + pass*16;
                const int ch = pA ^ (r & 15);
                async_copy16(Wt + (size_t)r*KDIM + k0 + ch*8,
                             (char*)sh.b.sB + pass*4096 + wv*1024 + l*16);
            }
            __syncthreads();

            #pragma unroll
            for (int ks = 0; ks < 4; ++ks) {
                bf16x8 af[2], bfr[2];
                #pragma unroll
                for (int mt = 0; mt < 2; ++mt) {
                    const int row = mt*16 + m;
                    const int p   = (ks*4 + q) ^ (row & 15);
                    af[mt] = *(const bf16x8*)&sh.b.sA[row*GBK + p*8];
                }
                #pragma unroll
                for (int j = 0; j < 2; ++j) {
                    const int row = (wv*2 + j)*16 + m;
                    const int p   = (ks*4 + q) ^ (row & 15);
                    bfr[j] = *(const bf16x8*)&sh.b.sB[row*GBK + p*8];
                }
                #pragma unroll
                for (int mt = 0; mt < 2; ++mt)
                    #pragma unroll
                    for (int j = 0; j < 2; ++j)
                        acc[mt][j] = __builtin_amdgcn_mfma_f32_16x16x32_bf16(
                                         af[mt], bfr[j], acc[mt][j], 0, 0, 0);
            }
            __syncthreads();
        }

        #pragma unroll
        for (int mt = 0; mt < 2; ++mt)
            #pragma unroll
            for (int j = 0; j < 2; ++j)
                #pragma unroll
                for (int r = 0; r < 4; ++r)
                    out[(size_t)(m0 + mt*16 + q*4 + r)*COUT
                        + (wv*2+j)*16 + m] = acc[mt][j][r];
    }
}

// ---------------------------------------------------------------------------
// Fallback (round-1 fused kernel) if ws too small / shape mismatch
// ---------------------------------------------------------------------------
#define TM 8
#define WSTR (KP*CIN + 4)

__global__ __launch_bounds__(256, 2)
void kpconv_fused(const float* __restrict__ q_pts,
                  const float* __restrict__ s_pts,
                  const int*   __restrict__ nb,
                  const float* __restrict__ x,
                  const float* __restrict__ kpts,
                  const float* __restrict__ W,
                  float* __restrict__ out,
                  int N, int Ns)
{
    __shared__ float s_kp[KP*3];
    __shared__ float s_nd2[HN*3];
    __shared__ int   s_idx2[HN];
    __shared__ float s_w[KP][HN];
    __shared__ float s_wt[TM*WSTR];

    const int t  = threadIdx.x;
    const int n0 = (int)blockIdx.x * TM;
    if (t < KP*3) s_kp[t] = kpts[t];
    const int c = t & (CIN-1);
    const int g = t >> 7;

    for (int mm = 0; mm < TM; ++mm) {
        const int n = n0 + mm;
        if (t < HN) {
            float dx = 1e6f, dy = 1e6f, dz = 1e6f;
            int idx = 0;
            if (n < N) {
                idx = nb[n*HN + t];
                if (idx >= 0 && idx < Ns) {
                    dx = s_pts[idx*3+0] - q_pts[n*3+0];
                    dy = s_pts[idx*3+1] - q_pts[n*3+1];
                    dz = s_pts[idx*3+2] - q_pts[n*3+2];
                } else idx = 0;
            }
            s_idx2[t] = idx;
            s_nd2[t*3+0] = dx; s_nd2[t*3+1] = dy; s_nd2[t*3+2] = dz;
        }
        __syncthreads();
        for (int task = t; task < KP*HN; task += 256) {
            const int k = task / HN;
            const int h = task - k*HN;
            const float dx = s_nd2[h*3+0] - s_kp[k*3+0];
            const float dy = s_nd2[h*3+1] - s_kp[k*3+1];
            const float dz = s_nd2[h*3+2] - s_kp[k*3+2];
            s_w[k][h] = fmaxf(1.0f - sqrtf(dx*dx+dy*dy+dz*dz)*KP_EXT_INV, 0.0f);
        }
        __syncthreads();
        float facc[8];
        #pragma unroll
        for (int j = 0; j < 8; ++j) facc[j] = 0.0f;
        #pragma unroll 8
        for (int h = 0; h < HN; ++h) {
            const float xv = x[s_idx2[h]*CIN + c];
            #pragma unroll
            for (int j = 0; j < 8; ++j) {
                const int k = g + 2*j;
                if (k < KP) facc[j] += s_w[k][h] * xv;
            }
        }
        #pragma unroll
        for (int j = 0; j < 8; ++j) {
            const int k = g + 2*j;
            if (k < KP) s_wt[mm*WSTR + k*CIN + c] = facc[j];
        }
        __syncthreads();
    }

    const int m3 = t >> 5;
    const int d0 = (t & 31) * 4;
    const float* wm = &s_wt[m3*WSTR];
    float ax = 0.f, ay = 0.f, az = 0.f, aw = 0.f;
    #pragma unroll 4
    for (int kc = 0; kc < KP*CIN; ++kc) {
        const float  wvv = wm[kc];
        const float4 wr = *(const float4*)&W[kc*COUT + d0];
        ax += wvv * wr.x; ay += wvv * wr.y; az += wvv * wr.z; aw += wvv * wr.w;
    }
    const int n = n0 + m3;
    if (n < N) {
        float4 o; o.x = ax; o.y = ay; o.z = az; o.w = aw;
        *(float4*)&out[n*COUT + d0] = o;
    }
}

// ---------------------------------------------------------------------------
extern "C" void kernel_launch(void* const* d_in, const int* in_sizes, int n_in,
                              void* d_out, int out_size, void* d_ws, size_t ws_size,
                              hipStream_t stream) {
    const float* q_pts = (const float*)d_in[0];
    const float* s_pts = (const float*)d_in[1];
    const int*   nb    = (const int*)  d_in[2];
    const float* x     = (const float*)d_in[3];
    const float* kpts  = (const float*)d_in[4];
    const float* W     = (const float*)d_in[5];
    float* out = (float*)d_out;

    const int N  = in_sizes[0] / 3;
    const int Ns = in_sizes[1] / 3;
    const int nx = in_sizes[3];            // Ns*CIN

    const size_t needA = (size_t)N * KDIM * sizeof(__bf16);
    const size_t needB = (size_t)COUT * KDIM * sizeof(__bf16);
    const size_t needX = (size_t)nx * sizeof(__bf16);

    if (ws_size >= needA + needB + needX && (N % GBM) == 0 && (nx % 8) == 0
        && (KDIM % GBK) == 0) {
        __bf16* wsA = (__bf16*)d_ws;
        __bf16* wsB = (__bf16*)((char*)d_ws + needA);
        __bf16* wsX = (__bf16*)((char*)d_ws + needA + needB);

        const int nxB = (nx/8 + 255) / 256;
        const int nwB = KDIM / 32;
        hipLaunchKernelGGL(kpconv_prep, dim3(nxB + nwB), dim3(256), 0, stream,
                           x, W, wsX, wsB, nx, nxB);
        hipLaunchKernelGGL(kpconv_main, dim3(N/GBM), dim3(256), 0, stream,
                           q_pts, s_pts, nb, wsX, kpts, wsB, wsA, out, N, Ns);
    } else {
        const int grid = (N + TM - 1) / TM;
        hipLaunchKernelGGL(kpconv_fused, dim3(grid), dim3(256), 0, stream,
                           q_pts, s_pts, nb, x, kpts, W, out, N, Ns);
    }
}